// Round 1
// baseline (145.961 us; speedup 1.0000x reference)
//
#include <hip/hip_runtime.h>

typedef __attribute__((ext_vector_type(8))) short short8;
typedef __attribute__((ext_vector_type(4))) short short4v;
typedef __attribute__((ext_vector_type(4))) float float4v;

typedef const void __attribute__((address_space(1)))* gptr_t;
typedef void __attribute__((address_space(3)))* lptr_t;

__device__ __forceinline__ void gload_lds16(const void* g, void* l) {
    __builtin_amdgcn_global_load_lds((gptr_t)g, (lptr_t)l, 16, 0, 0);
}

__device__ __forceinline__ unsigned short f2bf(float f) {
    union { float f; unsigned int u; } v; v.f = f;
    unsigned int r = v.u + 0x7fffu + ((v.u >> 16) & 1u);
    return (unsigned short)(r >> 16);
}

__device__ __forceinline__ short8 frag_ld(const unsigned char* base, int row, int k2) {
    return *(const short8*)(base + row * 128 + (k2 ^ ((row & 7) << 4)));
}

__device__ __forceinline__ float4v mfma_bf16(short8 a, short8 b, float4v c) {
    return __builtin_amdgcn_mfma_f32_16x16x32_bf16(a, b, c, 0, 0, 0);
}

// out[a][b] = bf16(in[b][a]), 1024x1024
__global__ __launch_bounds__(256) void k_transpose_bf16(
        const float* __restrict__ in, unsigned short* __restrict__ out) {
    __shared__ float tile[32][33];
    int tx = threadIdx.x, ty = threadIdx.y;
    int x = blockIdx.x * 32 + tx;
    int ybase = blockIdx.y * 32;
#pragma unroll
    for (int j = 0; j < 4; j++)
        tile[ty + j * 8][tx] = in[(size_t)(ybase + ty + j * 8) * 1024 + x];
    __syncthreads();
    int ox = ybase + tx;
    int oybase = blockIdx.x * 32;
#pragma unroll
    for (int j = 0; j < 4; j++)
        out[(size_t)(oybase + ty + j * 8) * 1024 + ox] = f2bf(tile[tx][ty + j * 8]);
}

// conv-as-GEMM, one (kh,kw) slice per blockIdx.z; atomicAdd fp32 partials.
// A[m][ic] = peT[(2*oh+kh)*32 + 2*ow+kw][ic]  (zeros when out of bounds)
// B[k][oc] = conv_w[((s)*1024 + ic)][oc]
__global__ __launch_bounds__(256) void k_conv_gemm(
        const float* __restrict__ convw,          // [9216][4096]
        const unsigned short* __restrict__ peT,   // [1024][1024] bf16
        const unsigned short* __restrict__ zerobuf,
        float* __restrict__ y_acc)                // [256][4096]
{
    __shared__ __align__(16) unsigned char ldsA[16384];
    __shared__ __align__(16) unsigned char ldsB[16384];

    const int t  = threadIdx.x;
    const int nt = blockIdx.x;      // 0..31
    const int mt = blockIdx.y;      // 0..1
    const int s  = blockIdx.z;      // 0..8
    const int kh = s / 3, kw = s - kh * 3;
    const int ncol0 = nt * 128;

    const int l = t & 63, w = t >> 6;
    const int wm = w >> 1, wn = w & 1;
    const int l15 = l & 15;
    const int lk2 = (l >> 4) * 16;  // byte offset of lane's 8-k group

    float4v acc[4][4] = {};

    const unsigned short* asrc[4];
    int aok[4];
#pragma unroll
    for (int i = 0; i < 4; i++) {
        int idx = i * 256 + t;
        int r = idx >> 3, c8 = idx & 7;
        int m = mt * 128 + r;
        int oh = m >> 4, ow = m & 15;
        int ih = 2 * oh + kh, iw = 2 * ow + kw;
        bool ok = (ih < 32) && (iw < 32);
        // pre-swizzled source chunk (m173): LDS stays linear, reads XOR back
        asrc[i] = ok ? (peT + (size_t)(ih * 32 + iw) * 1024 + ((c8 ^ (r & 7)) * 8))
                     : zerobuf;
        aok[i] = ok ? ~0 : 0;
    }

    const size_t krow0 = (size_t)s * 1024;
    const int nq = (t & 31) << 2;   // this thread's 4 output channels (n)
    const int kq = (t >> 5) << 2;   // this thread's 4 k rows within a 32-half

    for (int k0 = 0; k0 < 1024; k0 += 64) {
        // stage A via global_load_lds (16B), swizzled source
#pragma unroll
        for (int i = 0; i < 4; i++) {
            int idx = i * 256 + t;
            gload_lds16(asrc[i] + (k0 & aok[i]), ldsA + idx * 16);
        }
        // stage B: coalesced float4 along oc, in-register 4x4 transpose,
        // swizzled ds_write_b64 into Bt_lds[n][k]
        float4v rb[2][4];
#pragma unroll
        for (int h = 0; h < 2; h++) {
            const float* gb = convw + (krow0 + k0 + h * 32 + kq) * 4096 + ncol0 + nq;
#pragma unroll
            for (int j = 0; j < 4; j++)
                rb[h][j] = *(const float4v*)(gb + (size_t)j * 4096);
        }
#pragma unroll
        for (int h = 0; h < 2; h++) {
            int klb2 = (h * 32 + kq) * 2;
#pragma unroll
            for (int i = 0; i < 4; i++) {
                int n = nq + i;
                short4v v;
                v.x = (short)f2bf(rb[h][0][i]);
                v.y = (short)f2bf(rb[h][1][i]);
                v.z = (short)f2bf(rb[h][2][i]);
                v.w = (short)f2bf(rb[h][3][i]);
                *(short4v*)(ldsB + n * 128 + (klb2 ^ ((n & 7) << 4))) = v;
            }
        }
        __syncthreads();

        short8 af[4][2], bfr[4][2];
#pragma unroll
        for (int mf = 0; mf < 4; mf++)
#pragma unroll
            for (int ks = 0; ks < 2; ks++)
                af[mf][ks] = frag_ld(ldsA, wm * 64 + mf * 16 + l15, ks * 64 + lk2);
#pragma unroll
        for (int nf = 0; nf < 4; nf++)
#pragma unroll
            for (int ks = 0; ks < 2; ks++)
                bfr[nf][ks] = frag_ld(ldsB, wn * 64 + nf * 16 + l15, ks * 64 + lk2);
#pragma unroll
        for (int mf = 0; mf < 4; mf++)
#pragma unroll
            for (int nf = 0; nf < 4; nf++)
#pragma unroll
                for (int ks = 0; ks < 2; ks++)
                    acc[mf][nf] = mfma_bf16(af[mf][ks], bfr[nf][ks], acc[mf][nf]);
        __syncthreads();
    }

#pragma unroll
    for (int mf = 0; mf < 4; mf++) {
        int row = mt * 128 + wm * 64 + mf * 16 + (l >> 4) * 4;
#pragma unroll
        for (int nf = 0; nf < 4; nf++) {
            int col = ncol0 + wn * 64 + nf * 16 + l15;
#pragma unroll
            for (int r = 0; r < 4; r++)
                atomicAdd(&y_acc[(size_t)(row + r) * 4096 + col], acc[mf][nf][r]);
        }
    }
}

// BN (moving stats) + LeakyReLU, scatter into positional image pos2img[y][x]
__global__ __launch_bounds__(256) void k_bn_pos2(
        const float* __restrict__ y_acc, const float* __restrict__ cb,
        const float* __restrict__ gamma, const float* __restrict__ beta,
        const float* __restrict__ mean, const float* __restrict__ var,
        float* __restrict__ pos2img) {
    int idx = blockIdx.x * 256 + threadIdx.x;   // [m=256][oc=4096]
    int m = idx >> 12, oc = idx & 4095;
    float v = y_acc[idx] + cb[oc];
    v = (v - mean[oc]) * (gamma[oc] * rsqrtf(var[oc] + 1e-3f)) + beta[oc];
    v = v > 0.0f ? v : 0.3f * v;
    int y = ((oc >> 6) << 4) + (m >> 4);
    int x = ((oc & 63) << 4) + (m & 15);
    pos2img[y * 1024 + x] = v;
}

// enc0[b,n0,d0] = X[b,y,x] + pos2img[y,x] + W_emb[n0,d0], cast bf16
__global__ __launch_bounds__(256) void k_build_A(
        const float* __restrict__ X, const float* __restrict__ pos2img,
        const float* __restrict__ W_emb, unsigned short* __restrict__ Aenc) {
    int row = blockIdx.x;            // b*1024 + n0
    int n0 = row & 1023;
    int b  = row >> 10;
    int d0 = threadIdx.x * 4;
    int y = ((n0 >> 5) << 5) + (d0 >> 5);
    int x = ((n0 & 31) << 5) + (d0 & 31);
    size_t pix = (size_t)y * 1024 + x;
    float4v xv = *(const float4v*)(X + (size_t)b * 1048576 + pix);
    float4v pv = *(const float4v*)(pos2img + pix);
    float4v wv = *(const float4v*)(W_emb + (size_t)n0 * 1024 + d0);
    short4v o;
    o.x = (short)f2bf(xv.x + pv.x + wv.x);
    o.y = (short)f2bf(xv.y + pv.y + wv.y);
    o.z = (short)f2bf(xv.z + pv.z + wv.z);
    o.w = (short)f2bf(xv.w + pv.w + wv.w);
    *(short4v*)(Aenc + (size_t)row * 1024 + d0) = o;
}

// C[8192][1024] = A[8192][1024] * W_dense[1024][1024] + bias, bf16 MFMA
__global__ __launch_bounds__(256) void k_final_gemm(
        const unsigned short* __restrict__ A,   // [8192][1024] bf16
        const unsigned short* __restrict__ Bt,  // [1024][1024] bf16 = W_dense^T
        const float* __restrict__ bias,
        float* __restrict__ C) {
    __shared__ __align__(16) unsigned char ldsA[16384];
    __shared__ __align__(16) unsigned char ldsB[16384];
    const int t = threadIdx.x;
    const int col0 = blockIdx.x * 128;
    const int row0 = blockIdx.y * 128;
    const int l = t & 63, w = t >> 6;
    const int wm = w >> 1, wn = w & 1;
    const int l15 = l & 15;
    const int lk2 = (l >> 4) * 16;

    float4v acc[4][4] = {};

    const unsigned short* asrc[4];
    const unsigned short* bsrc[4];
#pragma unroll
    for (int i = 0; i < 4; i++) {
        int idx = i * 256 + t;
        int r = idx >> 3, c8 = idx & 7;
        int cofs = (c8 ^ (r & 7)) * 8;
        asrc[i] = A  + (size_t)(row0 + r) * 1024 + cofs;
        bsrc[i] = Bt + (size_t)(col0 + r) * 1024 + cofs;
    }

    for (int k0 = 0; k0 < 1024; k0 += 64) {
#pragma unroll
        for (int i = 0; i < 4; i++) {
            int idx = i * 256 + t;
            gload_lds16(asrc[i] + k0, ldsA + idx * 16);
            gload_lds16(bsrc[i] + k0, ldsB + idx * 16);
        }
        __syncthreads();

        short8 af[4][2], bfr[4][2];
#pragma unroll
        for (int mf = 0; mf < 4; mf++)
#pragma unroll
            for (int ks = 0; ks < 2; ks++)
                af[mf][ks] = frag_ld(ldsA, wm * 64 + mf * 16 + l15, ks * 64 + lk2);
#pragma unroll
        for (int nf = 0; nf < 4; nf++)
#pragma unroll
            for (int ks = 0; ks < 2; ks++)
                bfr[nf][ks] = frag_ld(ldsB, wn * 64 + nf * 16 + l15, ks * 64 + lk2);
#pragma unroll
        for (int mf = 0; mf < 4; mf++)
#pragma unroll
            for (int nf = 0; nf < 4; nf++)
#pragma unroll
                for (int ks = 0; ks < 2; ks++)
                    acc[mf][nf] = mfma_bf16(af[mf][ks], bfr[nf][ks], acc[mf][nf]);
        __syncthreads();
    }

#pragma unroll
    for (int nf = 0; nf < 4; nf++) {
        int col = col0 + wn * 64 + nf * 16 + l15;
        float bv = bias[col];
#pragma unroll
        for (int mf = 0; mf < 4; mf++) {
            int row = row0 + wm * 64 + mf * 16 + (l >> 4) * 4;
#pragma unroll
            for (int r = 0; r < 4; r++)
                C[(size_t)(row + r) * 1024 + col] = acc[mf][nf][r] + bv;
        }
    }
}

extern "C" void kernel_launch(void* const* d_in, const int* in_sizes, int n_in,
                              void* d_out, int out_size, void* d_ws, size_t ws_size,
                              hipStream_t stream) {
    (void)in_sizes; (void)n_in; (void)out_size; (void)ws_size;
    const float* X       = (const float*)d_in[0];
    const float* W_emb   = (const float*)d_in[1];
    const float* conv_w  = (const float*)d_in[2];
    const float* conv_b  = (const float*)d_in[3];
    const float* gamma   = (const float*)d_in[4];
    const float* beta    = (const float*)d_in[5];
    const float* mean    = (const float*)d_in[6];
    const float* var     = (const float*)d_in[7];
    const float* W_dense = (const float*)d_in[8];
    const float* b_dense = (const float*)d_in[9];
    float* out = (float*)d_out;

    unsigned char* ws = (unsigned char*)d_ws;
    float*          y_acc   = (float*)(ws);                       // 4 MB [256][4096]
    unsigned short* zerobuf = (unsigned short*)(ws + (4u << 20)); // 4 KB zeros
    unsigned short* peT     = (unsigned short*)(ws + (8u << 20)); // 2 MB bf16 W_emb^T
    unsigned short* WdT     = (unsigned short*)(ws + (10u << 20));// 2 MB bf16 W_dense^T
    float*          pos2img = (float*)(ws + (12u << 20));         // 4 MB [1024][1024]
    unsigned short* Aenc    = (unsigned short*)(ws + (16u << 20));// 16 MB bf16 [8192][1024]

    hipMemsetAsync(y_acc, 0, (4u << 20) + 4096, stream);

    dim3 tb(32, 8);
    k_transpose_bf16<<<dim3(32, 32), tb, 0, stream>>>(W_emb, peT);
    k_transpose_bf16<<<dim3(32, 32), tb, 0, stream>>>(W_dense, WdT);
    k_conv_gemm<<<dim3(32, 2, 9), 256, 0, stream>>>(conv_w, peT, zerobuf, y_acc);
    k_bn_pos2<<<4096, 256, 0, stream>>>(y_acc, conv_b, gamma, beta, mean, var, pos2img);
    k_build_A<<<8192, 256, 0, stream>>>(X, pos2img, W_emb, Aenc);
    k_final_gemm<<<dim3(8, 64), 256, 0, stream>>>(Aenc, WdT, b_dense, out);
}

// Round 2
// 117.804 us; speedup vs baseline: 1.2390x; 1.2390x over previous
//
#include <hip/hip_runtime.h>

typedef __attribute__((ext_vector_type(8))) short short8;
typedef __attribute__((ext_vector_type(4))) short short4v;
typedef __attribute__((ext_vector_type(4))) float float4v;

typedef const void __attribute__((address_space(1)))* gptr_t;
typedef void __attribute__((address_space(3)))* lptr_t;

__device__ __forceinline__ void gload_lds16(const void* g, void* l) {
    __builtin_amdgcn_global_load_lds((gptr_t)g, (lptr_t)l, 16, 0, 0);
}

__device__ __forceinline__ unsigned short f2bf(float f) {
    union { float f; unsigned int u; } v; v.f = f;
    unsigned int r = v.u + 0x7fffu + ((v.u >> 16) & 1u);
    return (unsigned short)(r >> 16);
}

__device__ __forceinline__ short8 frag_ld(const unsigned char* base, int row, int k2) {
    return *(const short8*)(base + row * 128 + (k2 ^ ((row & 7) << 4)));
}

// B-tile swizzle: mixes bit 3 of the row so that BOTH lane-stride-1 (frag reads)
// and lane-stride-4 (ds_writes) map 16 lanes onto all 8 16B slots, 2 lanes each.
__device__ __forceinline__ int swzB(int n) {
    return ((n ^ (n >> 3)) & 7) << 4;
}

__device__ __forceinline__ short8 frag_ldB(const unsigned char* base, int n, int k2) {
    return *(const short8*)(base + n * 128 + (k2 ^ swzB(n)));
}

__device__ __forceinline__ float4v mfma_bf16(short8 a, short8 b, float4v c) {
    return __builtin_amdgcn_mfma_f32_16x16x32_bf16(a, b, c, 0, 0, 0);
}

// out[a][b] = bf16(in[b][a]), 1024x1024
__global__ __launch_bounds__(256) void k_transpose_bf16(
        const float* __restrict__ in, unsigned short* __restrict__ out) {
    __shared__ float tile[32][33];
    int tx = threadIdx.x, ty = threadIdx.y;
    int x = blockIdx.x * 32 + tx;
    int ybase = blockIdx.y * 32;
#pragma unroll
    for (int j = 0; j < 4; j++)
        tile[ty + j * 8][tx] = in[(size_t)(ybase + ty + j * 8) * 1024 + x];
    __syncthreads();
    int ox = ybase + tx;
    int oybase = blockIdx.x * 32;
#pragma unroll
    for (int j = 0; j < 4; j++)
        out[(size_t)(oybase + ty + j * 8) * 1024 + ox] = f2bf(tile[tx][ty + j * 8]);
}

// conv-as-GEMM: tile M=128 (mt), N=64 (nt), one (kh,kw) slice per z; fp32 atomic out.
// Double-buffered LDS, prefetch next tile's loads before current tile's MFMA.
__global__ __launch_bounds__(256) void k_conv_gemm(
        const float* __restrict__ convw,          // [9216][4096]
        const unsigned short* __restrict__ peT,   // [1024][1024] bf16
        const unsigned short* __restrict__ zerobuf,
        float* __restrict__ y_acc)                // [256][4096]
{
    __shared__ __align__(16) unsigned char ldsA[2][16384]; // [128 m][64 k] bf16, swz (r&7)<<4
    __shared__ __align__(16) unsigned char ldsB[2][8192];  // [64 n][64 k] bf16, swzB

    const int t  = threadIdx.x;
    const int nt = blockIdx.x;      // 0..63
    const int mt = blockIdx.y;      // 0..1
    const int s  = blockIdx.z;      // 0..8
    const int kh = s / 3, kw = s - kh * 3;
    const int ncol0 = nt * 64;

    const int l = t & 63, w = t >> 6;
    const int wm = w >> 1, wn = w & 1;   // 2x2 wave grid, wave tile 64m x 32n
    const int l15 = l & 15;
    const int lk2 = (l >> 4) * 16;

    float4v acc[4][2] = {};

    // A staging sources: 4 x 16B chunks per thread, pre-swizzled global source
    const unsigned short* asrc[4];
    int aok[4];
#pragma unroll
    for (int i = 0; i < 4; i++) {
        int idx = i * 256 + t;
        int r = idx >> 3, c8 = idx & 7;
        int m = mt * 128 + r;
        int oh = m >> 4, ow = m & 15;
        int ih = 2 * oh + kh, iw = 2 * ow + kw;
        bool ok = (ih < 32) && (iw < 32);
        asrc[i] = ok ? (peT + (size_t)(ih * 32 + iw) * 1024 + ((c8 ^ (r & 7)) * 8))
                     : zerobuf;
        aok[i] = ok ? ~0 : 0;
    }

    // B: group g owns k-rows 4g..4g+3; lane16 owns n-cols 4*l16..4*l16+3
    const int g = t >> 4, l16v = t & 15;
    const int bk0 = g * 4;
    const int bn0 = l16v * 4;
    const float* bbase = convw + ((size_t)s * 1024 + bk0) * 4096 + ncol0 + bn0;

    for (int tt = 0; tt < 16; ++tt) {
        const int cur = tt & 1, nxt = cur ^ 1;

        if (tt == 0) {
            // prologue: stage tile 0 into buf 0
#pragma unroll
            for (int i = 0; i < 4; i++) {
                int idx = i * 256 + t;
                gload_lds16(asrc[i], &ldsA[0][idx * 16]);
            }
            float4v rb[4];
#pragma unroll
            for (int i = 0; i < 4; i++)
                rb[i] = *(const float4v*)(bbase + (size_t)i * 4096);
#pragma unroll
            for (int i = 0; i < 4; i++) {
                int n = bn0 + i;
                short4v v;
                v.x = (short)f2bf(rb[0][i]);
                v.y = (short)f2bf(rb[1][i]);
                v.z = (short)f2bf(rb[2][i]);
                v.w = (short)f2bf(rb[3][i]);
                *(short4v*)(&ldsB[0][n * 128 + ((bk0 * 2) ^ swzB(n))]) = v;
            }
            __syncthreads();
        }

        // prefetch next tile: issue loads BEFORE current tile's compute
        float4v rbn[4];
        if (tt < 15) {
            int k0n = (tt + 1) * 64;
#pragma unroll
            for (int i = 0; i < 4; i++) {
                int idx = i * 256 + t;
                gload_lds16(asrc[i] + (k0n & aok[i]), &ldsA[nxt][idx * 16]);
            }
#pragma unroll
            for (int i = 0; i < 4; i++)
                rbn[i] = *(const float4v*)(bbase + (size_t)(k0n + i) * 4096);
        }

        // compute current tile
        short8 af[4][2], bfr[2][2];
#pragma unroll
        for (int mf = 0; mf < 4; mf++)
#pragma unroll
            for (int ks = 0; ks < 2; ks++)
                af[mf][ks] = frag_ld(ldsA[cur], wm * 64 + mf * 16 + l15, ks * 64 + lk2);
#pragma unroll
        for (int nf = 0; nf < 2; nf++)
#pragma unroll
            for (int ks = 0; ks < 2; ks++)
                bfr[nf][ks] = frag_ldB(ldsB[cur], wn * 32 + nf * 16 + l15, ks * 64 + lk2);
#pragma unroll
        for (int mf = 0; mf < 4; mf++)
#pragma unroll
            for (int nf = 0; nf < 2; nf++)
#pragma unroll
                for (int ks = 0; ks < 2; ks++)
                    acc[mf][nf] = mfma_bf16(af[mf][ks], bfr[nf][ks], acc[mf][nf]);

        // write prefetched B into the other buffer
        if (tt < 15) {
#pragma unroll
            for (int i = 0; i < 4; i++) {
                int n = bn0 + i;
                short4v v;
                v.x = (short)f2bf(rbn[0][i]);
                v.y = (short)f2bf(rbn[1][i]);
                v.z = (short)f2bf(rbn[2][i]);
                v.w = (short)f2bf(rbn[3][i]);
                *(short4v*)(&ldsB[nxt][n * 128 + ((bk0 * 2) ^ swzB(n))]) = v;
            }
        }
        __syncthreads();
    }

#pragma unroll
    for (int mf = 0; mf < 4; mf++) {
        int row = mt * 128 + wm * 64 + mf * 16 + (l >> 4) * 4;
#pragma unroll
        for (int nf = 0; nf < 2; nf++) {
            int col = ncol0 + wn * 32 + nf * 16 + l15;
#pragma unroll
            for (int r = 0; r < 4; r++)
                atomicAdd(&y_acc[(size_t)(row + r) * 4096 + col], acc[mf][nf][r]);
        }
    }
}

// BN (moving stats) + LeakyReLU, scatter into positional image pos2img[y][x]
__global__ __launch_bounds__(256) void k_bn_pos2(
        const float* __restrict__ y_acc, const float* __restrict__ cb,
        const float* __restrict__ gamma, const float* __restrict__ beta,
        const float* __restrict__ mean, const float* __restrict__ var,
        float* __restrict__ pos2img) {
    int idx = blockIdx.x * 256 + threadIdx.x;   // [m=256][oc=4096]
    int m = idx >> 12, oc = idx & 4095;
    float v = y_acc[idx] + cb[oc];
    v = (v - mean[oc]) * (gamma[oc] * rsqrtf(var[oc] + 1e-3f)) + beta[oc];
    v = v > 0.0f ? v : 0.3f * v;
    int y = ((oc >> 6) << 4) + (m >> 4);
    int x = ((oc & 63) << 4) + (m & 15);
    pos2img[y * 1024 + x] = v;
}

// enc0[b,n0,d0] = X[b,y,x] + pos2img[y,x] + W_emb[n0,d0], cast bf16
__global__ __launch_bounds__(256) void k_build_A(
        const float* __restrict__ X, const float* __restrict__ pos2img,
        const float* __restrict__ W_emb, unsigned short* __restrict__ Aenc) {
    int row = blockIdx.x;            // b*1024 + n0
    int n0 = row & 1023;
    int b  = row >> 10;
    int d0 = threadIdx.x * 4;
    int y = ((n0 >> 5) << 5) + (d0 >> 5);
    int x = ((n0 & 31) << 5) + (d0 & 31);
    size_t pix = (size_t)y * 1024 + x;
    float4v xv = *(const float4v*)(X + (size_t)b * 1048576 + pix);
    float4v pv = *(const float4v*)(pos2img + pix);
    float4v wv = *(const float4v*)(W_emb + (size_t)n0 * 1024 + d0);
    short4v o;
    o.x = (short)f2bf(xv.x + pv.x + wv.x);
    o.y = (short)f2bf(xv.y + pv.y + wv.y);
    o.z = (short)f2bf(xv.z + pv.z + wv.z);
    o.w = (short)f2bf(xv.w + pv.w + wv.w);
    *(short4v*)(Aenc + (size_t)row * 1024 + d0) = o;
}

// C[8192][1024] = A[8192][1024] * W_dense[1024][1024] + bias, bf16 MFMA
__global__ __launch_bounds__(256) void k_final_gemm(
        const unsigned short* __restrict__ A,   // [8192][1024] bf16
        const unsigned short* __restrict__ Bt,  // [1024][1024] bf16 = W_dense^T
        const float* __restrict__ bias,
        float* __restrict__ C) {
    __shared__ __align__(16) unsigned char ldsA[16384];
    __shared__ __align__(16) unsigned char ldsB[16384];
    const int t = threadIdx.x;
    const int col0 = blockIdx.x * 128;
    const int row0 = blockIdx.y * 128;
    const int l = t & 63, w = t >> 6;
    const int wm = w >> 1, wn = w & 1;
    const int l15 = l & 15;
    const int lk2 = (l >> 4) * 16;

    float4v acc[4][4] = {};

    const unsigned short* asrc[4];
    const unsigned short* bsrc[4];
#pragma unroll
    for (int i = 0; i < 4; i++) {
        int idx = i * 256 + t;
        int r = idx >> 3, c8 = idx & 7;
        int cofs = (c8 ^ (r & 7)) * 8;
        asrc[i] = A  + (size_t)(row0 + r) * 1024 + cofs;
        bsrc[i] = Bt + (size_t)(col0 + r) * 1024 + cofs;
    }

    for (int k0 = 0; k0 < 1024; k0 += 64) {
#pragma unroll
        for (int i = 0; i < 4; i++) {
            int idx = i * 256 + t;
            gload_lds16(asrc[i] + k0, ldsA + idx * 16);
            gload_lds16(bsrc[i] + k0, ldsB + idx * 16);
        }
        __syncthreads();

        short8 af[4][2], bfr[4][2];
#pragma unroll
        for (int mf = 0; mf < 4; mf++)
#pragma unroll
            for (int ks = 0; ks < 2; ks++)
                af[mf][ks] = frag_ld(ldsA, wm * 64 + mf * 16 + l15, ks * 64 + lk2);
#pragma unroll
        for (int nf = 0; nf < 4; nf++)
#pragma unroll
            for (int ks = 0; ks < 2; ks++)
                bfr[nf][ks] = frag_ld(ldsB, wn * 64 + nf * 16 + l15, ks * 64 + lk2);
#pragma unroll
        for (int mf = 0; mf < 4; mf++)
#pragma unroll
            for (int nf = 0; nf < 4; nf++)
#pragma unroll
                for (int ks = 0; ks < 2; ks++)
                    acc[mf][nf] = mfma_bf16(af[mf][ks], bfr[nf][ks], acc[mf][nf]);
        __syncthreads();
    }

#pragma unroll
    for (int nf = 0; nf < 4; nf++) {
        int col = col0 + wn * 64 + nf * 16 + l15;
        float bv = bias[col];
#pragma unroll
        for (int mf = 0; mf < 4; mf++) {
            int row = row0 + wm * 64 + mf * 16 + (l >> 4) * 4;
#pragma unroll
            for (int r = 0; r < 4; r++)
                C[(size_t)(row + r) * 1024 + col] = acc[mf][nf][r] + bv;
        }
    }
}

extern "C" void kernel_launch(void* const* d_in, const int* in_sizes, int n_in,
                              void* d_out, int out_size, void* d_ws, size_t ws_size,
                              hipStream_t stream) {
    (void)in_sizes; (void)n_in; (void)out_size; (void)ws_size;
    const float* X       = (const float*)d_in[0];
    const float* W_emb   = (const float*)d_in[1];
    const float* conv_w  = (const float*)d_in[2];
    const float* conv_b  = (const float*)d_in[3];
    const float* gamma   = (const float*)d_in[4];
    const float* beta    = (const float*)d_in[5];
    const float* mean    = (const float*)d_in[6];
    const float* var     = (const float*)d_in[7];
    const float* W_dense = (const float*)d_in[8];
    const float* b_dense = (const float*)d_in[9];
    float* out = (float*)d_out;

    unsigned char* ws = (unsigned char*)d_ws;
    float*          y_acc   = (float*)(ws);                       // 4 MB [256][4096]
    unsigned short* zerobuf = (unsigned short*)(ws + (4u << 20)); // 4 KB zeros
    unsigned short* peT     = (unsigned short*)(ws + (8u << 20)); // 2 MB bf16 W_emb^T
    unsigned short* WdT     = (unsigned short*)(ws + (10u << 20));// 2 MB bf16 W_dense^T
    float*          pos2img = (float*)(ws + (12u << 20));         // 4 MB [1024][1024]
    unsigned short* Aenc    = (unsigned short*)(ws + (16u << 20));// 16 MB bf16 [8192][1024]

    hipMemsetAsync(y_acc, 0, (4u << 20) + 4096, stream);

    dim3 tb(32, 8);
    k_transpose_bf16<<<dim3(32, 32), tb, 0, stream>>>(W_emb, peT);
    k_transpose_bf16<<<dim3(32, 32), tb, 0, stream>>>(W_dense, WdT);
    k_conv_gemm<<<dim3(64, 2, 9), 256, 0, stream>>>(conv_w, peT, zerobuf, y_acc);
    k_bn_pos2<<<4096, 256, 0, stream>>>(y_acc, conv_b, gamma, beta, mean, var, pos2img);
    k_build_A<<<8192, 256, 0, stream>>>(X, pos2img, W_emb, Aenc);
    k_final_gemm<<<dim3(8, 64), 256, 0, stream>>>(Aenc, WdT, b_dense, out);
}

// Round 3
// 108.516 us; speedup vs baseline: 1.3451x; 1.0856x over previous
//
#include <hip/hip_runtime.h>

typedef __attribute__((ext_vector_type(8))) short short8;
typedef __attribute__((ext_vector_type(4))) short short4v;
typedef __attribute__((ext_vector_type(4))) float float4v;

typedef const void __attribute__((address_space(1)))* gptr_t;
typedef void __attribute__((address_space(3)))* lptr_t;

__device__ __forceinline__ void gload_lds16(const void* g, void* l) {
    __builtin_amdgcn_global_load_lds((gptr_t)g, (lptr_t)l, 16, 0, 0);
}

__device__ __forceinline__ unsigned short f2bf(float f) {
    union { float f; unsigned int u; } v; v.f = f;
    unsigned int r = v.u + 0x7fffu + ((v.u >> 16) & 1u);
    return (unsigned short)(r >> 16);
}

__device__ __forceinline__ short8 frag_ld(const unsigned char* base, int row, int k2) {
    return *(const short8*)(base + row * 128 + (k2 ^ ((row & 7) << 4)));
}

// B-tile swizzle: conflict-free for both lane-stride-1 reads and lane-stride-4 writes
__device__ __forceinline__ int swzB(int n) {
    return ((n ^ (n >> 3)) & 7) << 4;
}

__device__ __forceinline__ short8 frag_ldB(const unsigned char* base, int n, int k2) {
    return *(const short8*)(base + n * 128 + (k2 ^ swzB(n)));
}

__device__ __forceinline__ float4v mfma_bf16(short8 a, short8 b, float4v c) {
    return __builtin_amdgcn_mfma_f32_16x16x32_bf16(a, b, c, 0, 0, 0);
}

// out[a][b] = bf16(in[b][a]), 1024x1024
__global__ __launch_bounds__(256) void k_transpose_bf16(
        const float* __restrict__ in, unsigned short* __restrict__ out) {
    __shared__ float tile[32][33];
    int tx = threadIdx.x, ty = threadIdx.y;
    int x = blockIdx.x * 32 + tx;
    int ybase = blockIdx.y * 32;
#pragma unroll
    for (int j = 0; j < 4; j++)
        tile[ty + j * 8][tx] = in[(size_t)(ybase + ty + j * 8) * 1024 + x];
    __syncthreads();
    int ox = ybase + tx;
    int oybase = blockIdx.x * 32;
#pragma unroll
    for (int j = 0; j < 4; j++)
        out[(size_t)(oybase + ty + j * 8) * 1024 + ox] = f2bf(tile[tx][ty + j * 8]);
}

// conv-as-GEMM: tile M=128, N=64, one (kh,kw) slice per s; fp32 atomic out.
// 2-deep counted-vmcnt pipeline (T3/T4), raw s_barrier, XCD-chunked swizzle.
__global__ __launch_bounds__(256) void k_conv_gemm(
        const float* __restrict__ convw,          // [9216][4096]
        const unsigned short* __restrict__ peT,   // [1024][1024] bf16
        const unsigned short* __restrict__ zerobuf,
        float* __restrict__ y_acc)                // [256][4096]
{
    __shared__ __align__(16) unsigned char ldsA[2][16384]; // [128 m][64 k] bf16, swz (r&7)<<4
    __shared__ __align__(16) unsigned char ldsB[2][8192];  // [64 n][64 k] bf16, swzB

    const int t = threadIdx.x;
    // bijective XCD-chunked swizzle: nwg=1152, 1152/8=144. Logical order: mt fastest,
    // so mt-twins (sharing the same conv_w slice) land in the same XCD chunk.
    const int L = blockIdx.x;
    const int ell = (L & 7) * 144 + (L >> 3);
    const int mt = ell & 1;
    const int nt = (ell >> 1) & 63;
    const int s  = ell >> 7;
    const int kh = s / 3, kw = s - kh * 3;
    const int ncol0 = nt * 64;

    const int l = t & 63, w = t >> 6;
    const int wm = w >> 1, wn = w & 1;   // 2x2 wave grid, wave tile 64m x 32n
    const int l15 = l & 15;
    const int lk2 = (l >> 4) * 16;

    float4v acc[4][2] = {};

    // A staging sources: 4 x 16B chunks per thread, pre-swizzled global source
    const unsigned short* asrc[4];
    int aok[4];
#pragma unroll
    for (int i = 0; i < 4; i++) {
        int idx = i * 256 + t;
        int r = idx >> 3, c8 = idx & 7;
        int m = mt * 128 + r;
        int oh = m >> 4, ow = m & 15;
        int ih = 2 * oh + kh, iw = 2 * ow + kw;
        bool ok = (ih < 32) && (iw < 32);
        asrc[i] = ok ? (peT + (size_t)(ih * 32 + iw) * 1024 + ((c8 ^ (r & 7)) * 8))
                     : zerobuf;
        aok[i] = ok ? ~0 : 0;
    }

    // B: group g owns k-rows 4g..4g+3; lane16 owns n-cols 4*l16..4*l16+3
    const int g = t >> 4, l16v = t & 15;
    const int bk0 = g * 4;
    const int bn0 = l16v * 4;
    const float* bbase = convw + ((size_t)s * 1024 + bk0) * 4096 + ncol0 + bn0;

    float4v rb[2][4];   // statically indexed (loop fully unrolled)

    // ---- prologue: issue batches 0 and 1, land 0, build tile 0 ----
#pragma unroll
    for (int i = 0; i < 4; i++)
        gload_lds16(asrc[i], &ldsA[0][(i * 256 + t) * 16]);
#pragma unroll
    for (int i = 0; i < 4; i++)
        rb[0][i] = *(const float4v*)(bbase + (size_t)i * 4096);
    __builtin_amdgcn_sched_barrier(0);          // pin batch-0 | batch-1 boundary
#pragma unroll
    for (int i = 0; i < 4; i++)
        gload_lds16(asrc[i] + (64 & aok[i]), &ldsA[1][(i * 256 + t) * 16]);
#pragma unroll
    for (int i = 0; i < 4; i++)
        rb[1][i] = *(const float4v*)(bbase + (size_t)(64 + i) * 4096);
    asm volatile("s_waitcnt vmcnt(8)" ::: "memory");   // batch 0 landed
    __builtin_amdgcn_sched_barrier(0);
#pragma unroll
    for (int i = 0; i < 4; i++) {
        int n = bn0 + i;
        short4v v;
        v.x = (short)f2bf(rb[0][0][i]);
        v.y = (short)f2bf(rb[0][1][i]);
        v.z = (short)f2bf(rb[0][2][i]);
        v.w = (short)f2bf(rb[0][3][i]);
        *(short4v*)(&ldsB[0][n * 128 + ((bk0 * 2) ^ swzB(n))]) = v;
    }
    asm volatile("s_waitcnt lgkmcnt(0)" ::: "memory");
    __builtin_amdgcn_s_barrier();               // tile 0 ready

    // ---- main loop: 16 K-steps, fully unrolled ----
#pragma unroll
    for (int tt = 0; tt < 16; ++tt) {
        const int cur = tt & 1;

        // frag reads for tile tt
        short8 af[4][2], bfr[2][2];
#pragma unroll
        for (int mf = 0; mf < 4; mf++)
#pragma unroll
            for (int ks = 0; ks < 2; ks++)
                af[mf][ks] = frag_ld(ldsA[cur], wm * 64 + mf * 16 + l15, ks * 64 + lk2);
#pragma unroll
        for (int nf = 0; nf < 2; nf++)
#pragma unroll
            for (int ks = 0; ks < 2; ks++)
                bfr[nf][ks] = frag_ldB(ldsB[cur], wn * 32 + nf * 16 + l15, ks * 64 + lk2);
        asm volatile("s_waitcnt lgkmcnt(0)" ::: "memory");  // my reads done
        __builtin_amdgcn_sched_barrier(0);
        __builtin_amdgcn_s_barrier();                       // ALL reads of buf[cur] done

        // issue batch tt+2 (overwrites ldsA[cur]; rb[cur] free since step tt-2)
        if (tt < 14) {
            const int k0n = (tt + 2) * 64;
#pragma unroll
            for (int i = 0; i < 4; i++)
                gload_lds16(asrc[i] + (k0n & aok[i]), &ldsA[cur][(i * 256 + t) * 16]);
#pragma unroll
            for (int i = 0; i < 4; i++)
                rb[cur][i] = *(const float4v*)(bbase + (size_t)(k0n + i) * 4096);
        }

        // MFMA on tile tt (overlaps the in-flight batches)
        __builtin_amdgcn_s_setprio(1);
#pragma unroll
        for (int mf = 0; mf < 4; mf++)
#pragma unroll
            for (int nf = 0; nf < 2; nf++)
#pragma unroll
                for (int ks = 0; ks < 2; ks++)
                    acc[mf][nf] = mfma_bf16(af[mf][ks], bfr[nf][ks], acc[mf][nf]);
        __builtin_amdgcn_s_setprio(0);

        if (tt < 15) {
            // land batch tt+1 (leave batch tt+2 in flight), build tile tt+1
            if (tt < 14) asm volatile("s_waitcnt vmcnt(8)" ::: "memory");
            else         asm volatile("s_waitcnt vmcnt(0)" ::: "memory");
            __builtin_amdgcn_sched_barrier(0);
#pragma unroll
            for (int i = 0; i < 4; i++) {
                int n = bn0 + i;
                short4v v;
                v.x = (short)f2bf(rb[cur ^ 1][0][i]);
                v.y = (short)f2bf(rb[cur ^ 1][1][i]);
                v.z = (short)f2bf(rb[cur ^ 1][2][i]);
                v.w = (short)f2bf(rb[cur ^ 1][3][i]);
                *(short4v*)(&ldsB[cur ^ 1][n * 128 + ((bk0 * 2) ^ swzB(n))]) = v;
            }
            asm volatile("s_waitcnt lgkmcnt(0)" ::: "memory");
            __builtin_amdgcn_sched_barrier(0);
            __builtin_amdgcn_s_barrier();                   // tile tt+1 ready
        }
    }

#pragma unroll
    for (int mf = 0; mf < 4; mf++) {
        int row = mt * 128 + wm * 64 + mf * 16 + (l >> 4) * 4;
#pragma unroll
        for (int nf = 0; nf < 2; nf++) {
            int col = ncol0 + wn * 32 + nf * 16 + l15;
#pragma unroll
            for (int r = 0; r < 4; r++)
                atomicAdd(&y_acc[(size_t)(row + r) * 4096 + col], acc[mf][nf][r]);
        }
    }
}

// BN (moving stats) + LeakyReLU, scatter into positional image pos2img[y][x]
__global__ __launch_bounds__(256) void k_bn_pos2(
        const float* __restrict__ y_acc, const float* __restrict__ cb,
        const float* __restrict__ gamma, const float* __restrict__ beta,
        const float* __restrict__ mean, const float* __restrict__ var,
        float* __restrict__ pos2img) {
    int idx = blockIdx.x * 256 + threadIdx.x;   // [m=256][oc=4096]
    int m = idx >> 12, oc = idx & 4095;
    float v = y_acc[idx] + cb[oc];
    v = (v - mean[oc]) * (gamma[oc] * rsqrtf(var[oc] + 1e-3f)) + beta[oc];
    v = v > 0.0f ? v : 0.3f * v;
    int y = ((oc >> 6) << 4) + (m >> 4);
    int x = ((oc & 63) << 4) + (m & 15);
    pos2img[y * 1024 + x] = v;
}

// enc0[b,n0,d0] = X[b,y,x] + pos2img[y,x] + W_emb[n0,d0], cast bf16
__global__ __launch_bounds__(256) void k_build_A(
        const float* __restrict__ X, const float* __restrict__ pos2img,
        const float* __restrict__ W_emb, unsigned short* __restrict__ Aenc) {
    int row = blockIdx.x;            // b*1024 + n0
    int n0 = row & 1023;
    int b  = row >> 10;
    int d0 = threadIdx.x * 4;
    int y = ((n0 >> 5) << 5) + (d0 >> 5);
    int x = ((n0 & 31) << 5) + (d0 & 31);
    size_t pix = (size_t)y * 1024 + x;
    float4v xv = *(const float4v*)(X + (size_t)b * 1048576 + pix);
    float4v pv = *(const float4v*)(pos2img + pix);
    float4v wv = *(const float4v*)(W_emb + (size_t)n0 * 1024 + d0);
    short4v o;
    o.x = (short)f2bf(xv.x + pv.x + wv.x);
    o.y = (short)f2bf(xv.y + pv.y + wv.y);
    o.z = (short)f2bf(xv.z + pv.z + wv.z);
    o.w = (short)f2bf(xv.w + pv.w + wv.w);
    *(short4v*)(Aenc + (size_t)row * 1024 + d0) = o;
}

// C[8192][1024] = A[8192][1024] * W_dense[1024][1024] + bias, bf16 MFMA
__global__ __launch_bounds__(256) void k_final_gemm(
        const unsigned short* __restrict__ A,   // [8192][1024] bf16
        const unsigned short* __restrict__ Bt,  // [1024][1024] bf16 = W_dense^T
        const float* __restrict__ bias,
        float* __restrict__ C) {
    __shared__ __align__(16) unsigned char ldsA[16384];
    __shared__ __align__(16) unsigned char ldsB[16384];
    const int t = threadIdx.x;
    // XCD-chunked swizzle: nwg=512, 512/8=64; each XCD keeps Bt (2MB) + 8 A-panels in L2
    const int L = blockIdx.x;
    const int ell = (L & 7) * 64 + (L >> 3);
    const int col0 = (ell & 7) * 128;
    const int row0 = (ell >> 3) * 128;
    const int l = t & 63, w = t >> 6;
    const int wm = w >> 1, wn = w & 1;
    const int l15 = l & 15;
    const int lk2 = (l >> 4) * 16;

    float4v acc[4][4] = {};

    const unsigned short* asrc[4];
    const unsigned short* bsrc[4];
#pragma unroll
    for (int i = 0; i < 4; i++) {
        int idx = i * 256 + t;
        int r = idx >> 3, c8 = idx & 7;
        int cofs = (c8 ^ (r & 7)) * 8;
        asrc[i] = A  + (size_t)(row0 + r) * 1024 + cofs;
        bsrc[i] = Bt + (size_t)(col0 + r) * 1024 + cofs;
    }

    for (int k0 = 0; k0 < 1024; k0 += 64) {
#pragma unroll
        for (int i = 0; i < 4; i++) {
            int idx = i * 256 + t;
            gload_lds16(asrc[i] + k0, ldsA + idx * 16);
            gload_lds16(bsrc[i] + k0, ldsB + idx * 16);
        }
        __syncthreads();

        short8 af[4][2], bfr[4][2];
#pragma unroll
        for (int mf = 0; mf < 4; mf++)
#pragma unroll
            for (int ks = 0; ks < 2; ks++)
                af[mf][ks] = frag_ld(ldsA, wm * 64 + mf * 16 + l15, ks * 64 + lk2);
#pragma unroll
        for (int nf = 0; nf < 4; nf++)
#pragma unroll
            for (int ks = 0; ks < 2; ks++)
                bfr[nf][ks] = frag_ld(ldsB, wn * 64 + nf * 16 + l15, ks * 64 + lk2);
#pragma unroll
        for (int mf = 0; mf < 4; mf++)
#pragma unroll
            for (int nf = 0; nf < 4; nf++)
#pragma unroll
                for (int ks = 0; ks < 2; ks++)
                    acc[mf][nf] = mfma_bf16(af[mf][ks], bfr[nf][ks], acc[mf][nf]);
        __syncthreads();
    }

#pragma unroll
    for (int nf = 0; nf < 4; nf++) {
        int col = col0 + wn * 64 + nf * 16 + l15;
        float bv = bias[col];
#pragma unroll
        for (int mf = 0; mf < 4; mf++) {
            int row = row0 + wm * 64 + mf * 16 + (l >> 4) * 4;
#pragma unroll
            for (int r = 0; r < 4; r++)
                C[(size_t)(row + r) * 1024 + col] = acc[mf][nf][r] + bv;
        }
    }
}

extern "C" void kernel_launch(void* const* d_in, const int* in_sizes, int n_in,
                              void* d_out, int out_size, void* d_ws, size_t ws_size,
                              hipStream_t stream) {
    (void)in_sizes; (void)n_in; (void)out_size; (void)ws_size;
    const float* X       = (const float*)d_in[0];
    const float* W_emb   = (const float*)d_in[1];
    const float* conv_w  = (const float*)d_in[2];
    const float* conv_b  = (const float*)d_in[3];
    const float* gamma   = (const float*)d_in[4];
    const float* beta    = (const float*)d_in[5];
    const float* mean    = (const float*)d_in[6];
    const float* var     = (const float*)d_in[7];
    const float* W_dense = (const float*)d_in[8];
    const float* b_dense = (const float*)d_in[9];
    float* out = (float*)d_out;

    unsigned char* ws = (unsigned char*)d_ws;
    float*          y_acc   = (float*)(ws);                       // 4 MB [256][4096]
    unsigned short* zerobuf = (unsigned short*)(ws + (4u << 20)); // 4 KB zeros
    unsigned short* peT     = (unsigned short*)(ws + (8u << 20)); // 2 MB bf16 W_emb^T
    unsigned short* WdT     = (unsigned short*)(ws + (10u << 20));// 2 MB bf16 W_dense^T
    float*          pos2img = (float*)(ws + (12u << 20));         // 4 MB [1024][1024]
    unsigned short* Aenc    = (unsigned short*)(ws + (16u << 20));// 16 MB bf16 [8192][1024]

    hipMemsetAsync(y_acc, 0, (4u << 20) + 4096, stream);

    dim3 tb(32, 8);
    k_transpose_bf16<<<dim3(32, 32), tb, 0, stream>>>(W_emb, peT);
    k_transpose_bf16<<<dim3(32, 32), tb, 0, stream>>>(W_dense, WdT);
    k_conv_gemm<<<1152, 256, 0, stream>>>(conv_w, peT, zerobuf, y_acc);
    k_bn_pos2<<<4096, 256, 0, stream>>>(y_acc, conv_b, gamma, beta, mean, var, pos2img);
    k_build_A<<<8192, 256, 0, stream>>>(X, pos2img, W_emb, Aenc);
    k_final_gemm<<<512, 256, 0, stream>>>(Aenc, WdT, b_dense, out);
}